// Round 14
// baseline (120.923 us; speedup 1.0000x reference)
//
#include <hip/hip_runtime.h>

namespace {
constexpr int S = 1024, I = 512;
constexpr float LNEPS = 1e-5f;
constexpr float SCALE = 0.35355339059327373f; // 8^-0.5
}

typedef float f32x2 __attribute__((ext_vector_type(2)));

// pairwise dot8 on f32x2 lanes; contracts to v_pk_fma_f32.
__device__ __forceinline__ float dot8p(const f32x2 x2[4], float4 a, float4 b) {
    f32x2 w0; w0.x = a.x; w0.y = a.y;
    f32x2 w1; w1.x = a.z; w1.y = a.w;
    f32x2 w2; w2.x = b.x; w2.y = b.y;
    f32x2 w3; w3.x = b.z; w3.y = b.w;
    f32x2 acc = x2[0] * w0;
    acc = x2[1] * w1 + acc;
    acc = x2[2] * w2 + acc;
    acc = x2[3] * w3 + acc;
    return acc.x + acc.y;
}

__device__ __forceinline__ void ln8(float4 a, float4 b, const float gm[8],
                                    const float bt[8], float x[8]) {
    x[0] = a.x; x[1] = a.y; x[2] = a.z; x[3] = a.w;
    x[4] = b.x; x[5] = b.y; x[6] = b.z; x[7] = b.w;
    float mu = 0.f;
#pragma unroll
    for (int c = 0; c < 8; c++) mu += x[c];
    mu *= 0.125f;
    float var = 0.f;
#pragma unroll
    for (int c = 0; c < 8; c++) { float d = x[c] - mu; var += d * d; }
    var *= 0.125f;
    float inv = rsqrtf(var + LNEPS);
#pragma unroll
    for (int c = 0; c < 8; c++) x[c] = (x[c] - mu) * inv * gm[c] + bt[c];
}

// 512 blocks x 1024 threads, ONE column per block, ONE row per thread.
// launch_bounds(1024,2) => min 2 BLOCKS/CU (confirmed min-blocks semantics)
// => 64-VGPR cap => 32 waves/CU (8/SIMD) — double R10/R12's coverage.
// Live set ~47 regs (x2,p,v,oacc2 + temps), genuinely fits 64 (unlike R5/R7).
// Exp2/xl2 experiment dropped (R13 regression): __expf direct.
__global__ __launch_bounds__(1024, 2) void fused(
    const float* __restrict__ m, const float* __restrict__ gamma,
    const float* __restrict__ beta, const float* __restrict__ Wq,
    const float* __restrict__ Wk, const float* __restrict__ Wv,
    const float* __restrict__ Wg, const float* __restrict__ Wo,
    const float* __restrict__ bo, float* __restrict__ out) {
    __shared__ __align__(16) float sWoT[512];     // sWoT[j][c2] = Wo[c2][j]
    __shared__ __align__(16) float swred[16 * 8]; // [wave][c]
    __shared__ __align__(16) float sxbar[8];
    __shared__ __align__(16) float sqk[64];       // [h*8+c2]
    __shared__ __align__(16) float srden[8];      // [h]

    int t = threadIdx.x;     // row s
    int w = t >> 6;          // wave id [0,16)
    int i = blockIdx.x;      // this block's column

    // ---- stage transposed Wo ----
    if (t < 512) {
        int j = t & 63, c2 = t >> 6;
        sWoT[j * 8 + c2] = Wo[c2 * 64 + j];
    }

    float gm[8], bt[8];
#pragma unroll
    for (int c = 0; c < 8; c++) { gm[c] = gamma[c]; bt[c] = beta[c]; }

    // ---- phase 1: load m once, LN, LN-sum reduce ----
    const float4* m4 = (const float4*)m;
    int row = t * I + i;
    float x[8];
    ln8(m4[row * 2], m4[row * 2 + 1], gm, bt, x);

    f32x2 x2[4];
#pragma unroll
    for (int j = 0; j < 4; j++) { x2[j].x = x[2 * j]; x2[j].y = x[2 * j + 1]; }

    {
        float acc[8];
#pragma unroll
        for (int c = 0; c < 8; c++) acc[c] = x[c];
#pragma unroll
        for (int d = 1; d < 64; d <<= 1)
#pragma unroll
            for (int c = 0; c < 8; c++) acc[c] += __shfl_xor(acc[c], d, 64);
        if ((t & 63) == 0) {
#pragma unroll
            for (int c = 0; c < 8; c++) swred[w * 8 + c] = acc[c];
        }
    }
    __syncthreads();   // S1 (also covers sWoT staging)
    if (t < 8) {
        float s = 0.f;
#pragma unroll
        for (int ww = 0; ww < 16; ww++) s += swred[ww * 8 + t];
        sxbar[t] = s;
    }
    __syncthreads();   // S2
    // qk[h][c2] = SCALE/S * sum_c (xbar . Wq_hc) Wk[c][c2]
    if (t < 64) {
        int h = t >> 3, c2 = t & 7;
        float a = 0.f;
#pragma unroll
        for (int c = 0; c < 8; c++) {
            float qc = 0.f;
#pragma unroll
            for (int c3 = 0; c3 < 8; c3++)
                qc += sxbar[c3] * Wq[(h * 8 + c) * 8 + c3];
            a += qc * Wk[c * 8 + c2];
        }
        sqk[t] = a * (SCALE / 1024.0f);
    }
    __syncthreads();   // S3

    // ---- phase 2: exp logits cached in p (static idx) + denominator ----
    const float4* sqk4 = (const float4*)sqk;
    float p[8];
    {
        float e[8];
#pragma unroll
        for (int h = 0; h < 8; h++) {
            p[h] = __expf(dot8p(x2, sqk4[h * 2], sqk4[h * 2 + 1]));
            e[h] = p[h];
        }
#pragma unroll
        for (int d = 1; d < 64; d <<= 1)
#pragma unroll
            for (int h = 0; h < 8; h++) e[h] += __shfl_xor(e[h], d, 64);
        if ((t & 63) == 0) {
#pragma unroll
            for (int h = 0; h < 8; h++) swred[w * 8 + h] = e[h];
        }
    }
    __syncthreads();   // S4
    if (t < 8) {
        float s = 0.f;
#pragma unroll
        for (int ww = 0; ww < 16; ww++) s += swred[ww * 8 + t];
        srden[t] = 1.0f / s;
    }
    __syncthreads();   // S5

    // pre-scale p by 1/denominator (uniform LDS broadcast, static p idx)
#pragma unroll
    for (int h = 0; h < 8; h++) p[h] *= srden[h];

    // ---- phase 3: fully unrolled packed output contraction ----
    const float4* Wv4 = (const float4*)Wv;
    const float4* Wg4 = (const float4*)Wg;
    const f32x2* sWoT2 = (const f32x2*)sWoT;

    float v[8];
#pragma unroll
    for (int c = 0; c < 8; c++)
        v[c] = dot8p(x2, Wv4[c * 2], Wv4[c * 2 + 1]);

    f32x2 oacc2[4];
#pragma unroll
    for (int j = 0; j < 4; j++) {
        oacc2[j].x = bo[2 * j]; oacc2[j].y = bo[2 * j + 1];
    }

#pragma unroll
    for (int c = 0; c < 8; c++) {
#pragma unroll
        for (int h = 0; h < 8; h++) {
            int hc = h * 8 + c;
            float z = dot8p(x2, Wg4[hc * 2], Wg4[hc * 2 + 1]);
            float gate = __builtin_amdgcn_rcpf(1.0f + __expf(-z));
            float o_ = gate * p[h] * v[c];
            f32x2 o2; o2.x = o_; o2.y = o_;
            oacc2[0] = o2 * sWoT2[hc * 4 + 0] + oacc2[0];  // v_pk_fma_f32
            oacc2[1] = o2 * sWoT2[hc * 4 + 1] + oacc2[1];
            oacc2[2] = o2 * sWoT2[hc * 4 + 2] + oacc2[2];
            oacc2[3] = o2 * sWoT2[hc * 4 + 3] + oacc2[3];
        }
    }
    float4* out4 = (float4*)out;
    out4[row * 2] = make_float4(oacc2[0].x, oacc2[0].y, oacc2[1].x, oacc2[1].y);
    out4[row * 2 + 1] = make_float4(oacc2[2].x, oacc2[2].y, oacc2[3].x, oacc2[3].y);
}

extern "C" void kernel_launch(void* const* d_in, const int* in_sizes, int n_in,
                              void* d_out, int out_size, void* d_ws, size_t ws_size,
                              hipStream_t stream) {
    const float* m     = (const float*)d_in[0];
    const float* gamma = (const float*)d_in[1];
    const float* beta  = (const float*)d_in[2];
    const float* Wq    = (const float*)d_in[3];
    const float* Wk    = (const float*)d_in[4];
    const float* Wv    = (const float*)d_in[5];
    const float* Wg    = (const float*)d_in[6];
    const float* Wo    = (const float*)d_in[7];
    const float* bo    = (const float*)d_in[8];
    float* out = (float*)d_out;

    fused<<<I, 1024, 0, stream>>>(m, gamma, beta, Wq, Wk, Wv, Wg, Wo, bo, out);
}

// Round 15
// 107.317 us; speedup vs baseline: 1.1268x; 1.1268x over previous
//
#include <hip/hip_runtime.h>

namespace {
constexpr int S = 1024, I = 512, C = 8, H = 8;
constexpr int R = 2;                 // rows per thread (per its column)
constexpr float LNEPS = 1e-5f;
constexpr float SCALE = 0.35355339059327373f; // 8^-0.5
}

typedef float f32x2 __attribute__((ext_vector_type(2)));

// pairwise dot8 on f32x2 lanes; contracts to v_pk_fma_f32.
__device__ __forceinline__ float dot8p(const f32x2 x2[4], float4 a, float4 b) {
    f32x2 w0; w0.x = a.x; w0.y = a.y;
    f32x2 w1; w1.x = a.z; w1.y = a.w;
    f32x2 w2; w2.x = b.x; w2.y = b.y;
    f32x2 w3; w3.x = b.z; w3.y = b.w;
    f32x2 acc = x2[0] * w0;
    acc = x2[1] * w1 + acc;
    acc = x2[2] * w2 + acc;
    acc = x2[3] * w3 + acc;
    return acc.x + acc.y;
}

__device__ __forceinline__ void ln8(float4 a, float4 b, const float gm[8],
                                    const float bt[8], float x[8]) {
    x[0] = a.x; x[1] = a.y; x[2] = a.z; x[3] = a.w;
    x[4] = b.x; x[5] = b.y; x[6] = b.z; x[7] = b.w;
    float mu = 0.f;
#pragma unroll
    for (int c = 0; c < 8; c++) mu += x[c];
    mu *= 0.125f;
    float var = 0.f;
#pragma unroll
    for (int c = 0; c < 8; c++) { float d = x[c] - mu; var += d * d; }
    var *= 0.125f;
    float inv = rsqrtf(var + LNEPS);
#pragma unroll
    for (int c = 0; c < 8; c++) x[c] = (x[c] - mu) * inv * gm[c] + bt[c];
}

// 256 blocks x 1024 threads, 2 columns/block, 2 rows/thread — R12 config
// (best verified: 106.5 total), occupancy ladder closed (2/4/8 w-SIMD =
// 53/44/50 µs: flat past 4). This rev attacks the LDS pipe: Wo fragments
// read as ds_read_b128 (2/combo = 128/thread) instead of 4x ds_read_b64
// (256/thread). Everything else identical to R12.
__global__ __launch_bounds__(1024) void fused(
    const float* __restrict__ m, const float* __restrict__ gamma,
    const float* __restrict__ beta, const float* __restrict__ Wq,
    const float* __restrict__ Wk, const float* __restrict__ Wv,
    const float* __restrict__ Wg, const float* __restrict__ Wo,
    const float* __restrict__ bo, float* __restrict__ out) {
    __shared__ __align__(16) float sWoT[512];      // sWoT[j][c2] = Wo[c2][j]
    __shared__ __align__(16) float swred[16 * 16]; // [wave][col*8+c]
    __shared__ __align__(16) float sxbar[16];      // [col][c]
    __shared__ __align__(16) float sqk[128];       // [col][h*8+c2]
    __shared__ __align__(16) float srden[16];      // [col][h]

    int t = threadIdx.x;
    int w = t >> 6;          // wave id [0,16)
    int col = t & 1;         // which of the block's 2 columns
    int si = t >> 1;         // [0,512): s = si + 512*r
    int i = 2 * blockIdx.x + col;

    // ---- stage transposed Wo ----
    if (t < 512) {
        int j = t & 63, c2 = t >> 6;
        sWoT[j * 8 + c2] = Wo[c2 * 64 + j];
    }

    float gm[8], bt[8];
#pragma unroll
    for (int c = 0; c < 8; c++) { gm[c] = gamma[c]; bt[c] = beta[c]; }

    // ---- phase 1: load m once, LN, per-thread LN-sum ----
    const float4* m4 = (const float4*)m;
    float x[R][8];
    float acc[8];
#pragma unroll
    for (int c = 0; c < 8; c++) acc[c] = 0.f;
#pragma unroll
    for (int r = 0; r < R; r++) {
        int row = (si + 512 * r) * I + i;
        ln8(m4[row * 2], m4[row * 2 + 1], gm, bt, x[r]);
#pragma unroll
        for (int c = 0; c < 8; c++) acc[c] += x[r][c];
    }
    // packed pairs of x for phase 2/3 dots: x2[r][j] = {x[2j], x[2j+1]}
    f32x2 x2[R][4];
#pragma unroll
    for (int r = 0; r < R; r++)
#pragma unroll
        for (int j = 0; j < 4; j++) {
            x2[r][j].x = x[r][2 * j]; x2[r][j].y = x[r][2 * j + 1];
        }

    // parity-preserving wave reduce (keeps col separate)
#pragma unroll
    for (int d = 2; d < 64; d <<= 1)
#pragma unroll
        for (int c = 0; c < 8; c++) acc[c] += __shfl_xor(acc[c], d, 64);
    if ((t & 63) < 2) {
#pragma unroll
        for (int c = 0; c < 8; c++) swred[w * 16 + col * 8 + c] = acc[c];
    }
    __syncthreads();   // S1 (also covers sWoT staging)
    if (t < 16) {      // col = t>>3, c = t&7
        float s = 0.f;
#pragma unroll
        for (int ww = 0; ww < 16; ww++) s += swred[ww * 16 + t];
        sxbar[t] = s;
    }
    __syncthreads();   // S2
    // qk[col][h][c2] = SCALE/S * sum_c (xbar . Wq_hc) Wk[c][c2]
    if (t < 128) {
        int qcol = t >> 6, h = (t >> 3) & 7, c2 = t & 7;
        float xb[8];
#pragma unroll
        for (int c3 = 0; c3 < 8; c3++) xb[c3] = sxbar[qcol * 8 + c3];
        float a = 0.f;
#pragma unroll
        for (int c = 0; c < 8; c++) {
            float qc = 0.f;
#pragma unroll
            for (int c3 = 0; c3 < 8; c3++)
                qc += xb[c3] * Wq[(h * 8 + c) * 8 + c3];
            a += qc * Wk[c * 8 + c2];
        }
        sqk[qcol * 64 + h * 8 + c2] = a * (SCALE / 1024.0f);
    }
    __syncthreads();   // S3

    // ---- phase 2: exp logits cached in p (static idx) + denominator ----
    const float4* sqk4 = (const float4*)sqk;
    float p[R][8];
    {
        float e[8];
#pragma unroll
        for (int h = 0; h < 8; h++) {
            float4 q0 = sqk4[col * 16 + h * 2], q1 = sqk4[col * 16 + h * 2 + 1];
            float s = 0.f;
#pragma unroll
            for (int r = 0; r < R; r++) {
                p[r][h] = __expf(dot8p(x2[r], q0, q1));
                s += p[r][h];
            }
            e[h] = s;
        }
#pragma unroll
        for (int d = 2; d < 64; d <<= 1)
#pragma unroll
            for (int h = 0; h < 8; h++) e[h] += __shfl_xor(e[h], d, 64);
        if ((t & 63) < 2) {
#pragma unroll
            for (int h = 0; h < 8; h++) swred[w * 16 + col * 8 + h] = e[h];
        }
    }
    __syncthreads();   // S4
    if (t < 16) {
        float s = 0.f;
#pragma unroll
        for (int ww = 0; ww < 16; ww++) s += swred[ww * 16 + t];
        srden[t] = 1.0f / s;
    }
    __syncthreads();   // S5

    // ppair[h] = {p0h, p1h} * 1/den  (static idx, packed)
    f32x2 ppair[8];
#pragma unroll
    for (int h = 0; h < 8; h++) {
        float rd = srden[col * 8 + h];
        ppair[h].x = p[0][h] * rd;
        ppair[h].y = p[1][h] * rd;
    }

    // ---- phase 3: FULLY unrolled, r-paired packed output contraction.
    //      Wo via 2x ds_read_b128 per combo (was 4x ds_read_b64). ----
    const float4* Wv4 = (const float4*)Wv;
    const float4* Wg4 = (const float4*)Wg;
    const float4* sWoT4 = (const float4*)sWoT;

    f32x2 oacc2[R][4];
#pragma unroll
    for (int r = 0; r < R; r++)
#pragma unroll
        for (int j = 0; j < 4; j++) {
            oacc2[r][j].x = bo[2 * j]; oacc2[r][j].y = bo[2 * j + 1];
        }

#pragma unroll
    for (int c = 0; c < 8; c++) {
        float4 wv0 = Wv4[c * 2], wv1 = Wv4[c * 2 + 1];
        f32x2 vpair;
        vpair.x = dot8p(x2[0], wv0, wv1);
        vpair.y = dot8p(x2[1], wv0, wv1);
#pragma unroll
        for (int h = 0; h < 8; h++) {
            int hc = h * 8 + c;
            float4 wg0 = Wg4[hc * 2], wg1 = Wg4[hc * 2 + 1];
            float4 woA = sWoT4[hc * 2];      // ds_read_b128: WoT[hc][0..3]
            float4 woB = sWoT4[hc * 2 + 1];  // ds_read_b128: WoT[hc][4..7]
            f32x2 wo0; wo0.x = woA.x; wo0.y = woA.y;   // VGPR-quad halves,
            f32x2 wo1; wo1.x = woA.z; wo1.y = woA.w;   // no moves needed
            f32x2 wo2; wo2.x = woB.x; wo2.y = woB.y;
            f32x2 wo3; wo3.x = woB.z; wo3.y = woB.w;
            float z0 = dot8p(x2[0], wg0, wg1);
            float z1 = dot8p(x2[1], wg0, wg1);
            f32x2 ez; ez.x = __expf(-z0); ez.y = __expf(-z1);
            f32x2 den = ez + 1.0f;                       // pk_add
            f32x2 g;
            g.x = __builtin_amdgcn_rcpf(den.x);
            g.y = __builtin_amdgcn_rcpf(den.y);
            f32x2 o = g * ppair[h] * vpair;              // 2 pk_mul
            f32x2 o0; o0.x = o.x; o0.y = o.x;            // op_sel splats
            f32x2 o1; o1.x = o.y; o1.y = o.y;
            oacc2[0][0] = o0 * wo0 + oacc2[0][0];
            oacc2[0][1] = o0 * wo1 + oacc2[0][1];
            oacc2[0][2] = o0 * wo2 + oacc2[0][2];
            oacc2[0][3] = o0 * wo3 + oacc2[0][3];
            oacc2[1][0] = o1 * wo0 + oacc2[1][0];
            oacc2[1][1] = o1 * wo1 + oacc2[1][1];
            oacc2[1][2] = o1 * wo2 + oacc2[1][2];
            oacc2[1][3] = o1 * wo3 + oacc2[1][3];
        }
    }
    float4* out4 = (float4*)out;
#pragma unroll
    for (int r = 0; r < R; r++) {
        int row = (si + 512 * r) * I + i;
        out4[row * 2] = make_float4(oacc2[r][0].x, oacc2[r][0].y,
                                    oacc2[r][1].x, oacc2[r][1].y);
        out4[row * 2 + 1] = make_float4(oacc2[r][2].x, oacc2[r][2].y,
                                        oacc2[r][3].x, oacc2[r][3].y);
    }
}

extern "C" void kernel_launch(void* const* d_in, const int* in_sizes, int n_in,
                              void* d_out, int out_size, void* d_ws, size_t ws_size,
                              hipStream_t stream) {
    const float* m     = (const float*)d_in[0];
    const float* gamma = (const float*)d_in[1];
    const float* beta  = (const float*)d_in[2];
    const float* Wq    = (const float*)d_in[3];
    const float* Wk    = (const float*)d_in[4];
    const float* Wv    = (const float*)d_in[5];
    const float* Wg    = (const float*)d_in[6];
    const float* Wo    = (const float*)d_in[7];
    const float* bo    = (const float*)d_in[8];
    float* out = (float*)d_out;

    fused<<<I / 2, 1024, 0, stream>>>(m, gamma, beta, Wq, Wk, Wv, Wg, Wo, bo, out);
}

// Round 16
// 106.302 us; speedup vs baseline: 1.1375x; 1.0096x over previous
//
#include <hip/hip_runtime.h>

namespace {
constexpr int S = 1024, I = 512, C = 8, H = 8;
constexpr int R = 2;                 // rows per thread (per its column)
constexpr float LNEPS = 1e-5f;
constexpr float SCALE = 0.35355339059327373f; // 8^-0.5
}

typedef float f32x2 __attribute__((ext_vector_type(2)));

// pairwise dot8 on f32x2 lanes; contracts to v_pk_fma_f32.
__device__ __forceinline__ float dot8p(const f32x2 x2[4], float4 a, float4 b) {
    f32x2 w0; w0.x = a.x; w0.y = a.y;
    f32x2 w1; w1.x = a.z; w1.y = a.w;
    f32x2 w2; w2.x = b.x; w2.y = b.y;
    f32x2 w3; w3.x = b.z; w3.y = b.w;
    f32x2 acc = x2[0] * w0;
    acc = x2[1] * w1 + acc;
    acc = x2[2] * w2 + acc;
    acc = x2[3] * w3 + acc;
    return acc.x + acc.y;
}

__device__ __forceinline__ void ln8(float4 a, float4 b, const float gm[8],
                                    const float bt[8], float x[8]) {
    x[0] = a.x; x[1] = a.y; x[2] = a.z; x[3] = a.w;
    x[4] = b.x; x[5] = b.y; x[6] = b.z; x[7] = b.w;
    float mu = 0.f;
#pragma unroll
    for (int c = 0; c < 8; c++) mu += x[c];
    mu *= 0.125f;
    float var = 0.f;
#pragma unroll
    for (int c = 0; c < 8; c++) { float d = x[c] - mu; var += d * d; }
    var *= 0.125f;
    float inv = rsqrtf(var + LNEPS);
#pragma unroll
    for (int c = 0; c < 8; c++) x[c] = (x[c] - mu) * inv * gm[c] + bt[c];
}

// 256 blocks x 1024 threads, 2 columns/block, 2 rows/thread (R12 base).
// This rev: Wg and Wv staged to LDS too (all phase-3 weights LDS-resident,
// uniform ds_read_b128 broadcasts). Theory: the in-loop wave-uniform
// s_load_dwordx4 stream for Wg (128/wave, SGPR-budget-limited -> periodic
// lgkmcnt fences at K$ latency) is the occupancy-invariant stall seen at
// 2/4/8 waves/SIMD. LDS reads pipeline deeply into VGPRs instead.
__global__ __launch_bounds__(1024) void fused(
    const float* __restrict__ m, const float* __restrict__ gamma,
    const float* __restrict__ beta, const float* __restrict__ Wq,
    const float* __restrict__ Wk, const float* __restrict__ Wv,
    const float* __restrict__ Wg, const float* __restrict__ Wo,
    const float* __restrict__ bo, float* __restrict__ out) {
    __shared__ __align__(16) float sWoT[512];      // sWoT[j][c2] = Wo[c2][j]
    __shared__ __align__(16) float sWg[512];       // Wg[hc][c3]
    __shared__ __align__(16) float sWv[64];        // Wv[c][c3]
    __shared__ __align__(16) float swred[16 * 16]; // [wave][col*8+c]
    __shared__ __align__(16) float sxbar[16];      // [col][c]
    __shared__ __align__(16) float sqk[128];       // [col][h*8+c2]
    __shared__ __align__(16) float srden[16];      // [col][h]

    int t = threadIdx.x;
    int w = t >> 6;          // wave id [0,16)
    int col = t & 1;         // which of the block's 2 columns
    int si = t >> 1;         // [0,512): s = si + 512*r
    int i = 2 * blockIdx.x + col;

    // ---- stage weights: WoT (transposed), Wg, Wv ----
    if (t < 512) {
        int j = t & 63, c2 = t >> 6;
        sWoT[j * 8 + c2] = Wo[c2 * 64 + j];
        if (t < 64) sWv[t] = Wv[t];
    } else {
        sWg[t - 512] = Wg[t - 512];
    }

    float gm[8], bt[8];
#pragma unroll
    for (int c = 0; c < 8; c++) { gm[c] = gamma[c]; bt[c] = beta[c]; }

    // ---- phase 1: load m once, LN, per-thread LN-sum ----
    const float4* m4 = (const float4*)m;
    float x[R][8];
    float acc[8];
#pragma unroll
    for (int c = 0; c < 8; c++) acc[c] = 0.f;
#pragma unroll
    for (int r = 0; r < R; r++) {
        int row = (si + 512 * r) * I + i;
        ln8(m4[row * 2], m4[row * 2 + 1], gm, bt, x[r]);
#pragma unroll
        for (int c = 0; c < 8; c++) acc[c] += x[r][c];
    }
    // packed pairs of x for phase 2/3 dots: x2[r][j] = {x[2j], x[2j+1]}
    f32x2 x2[R][4];
#pragma unroll
    for (int r = 0; r < R; r++)
#pragma unroll
        for (int j = 0; j < 4; j++) {
            x2[r][j].x = x[r][2 * j]; x2[r][j].y = x[r][2 * j + 1];
        }

    // parity-preserving wave reduce (keeps col separate)
#pragma unroll
    for (int d = 2; d < 64; d <<= 1)
#pragma unroll
        for (int c = 0; c < 8; c++) acc[c] += __shfl_xor(acc[c], d, 64);
    if ((t & 63) < 2) {
#pragma unroll
        for (int c = 0; c < 8; c++) swred[w * 16 + col * 8 + c] = acc[c];
    }
    __syncthreads();   // S1 (also covers weight staging)
    if (t < 16) {      // col = t>>3, c = t&7
        float s = 0.f;
#pragma unroll
        for (int ww = 0; ww < 16; ww++) s += swred[ww * 16 + t];
        sxbar[t] = s;
    }
    __syncthreads();   // S2
    // qk[col][h][c2] = SCALE/S * sum_c (xbar . Wq_hc) Wk[c][c2]
    if (t < 128) {
        int qcol = t >> 6, h = (t >> 3) & 7, c2 = t & 7;
        float xb[8];
#pragma unroll
        for (int c3 = 0; c3 < 8; c3++) xb[c3] = sxbar[qcol * 8 + c3];
        float a = 0.f;
#pragma unroll
        for (int c = 0; c < 8; c++) {
            float qc = 0.f;
#pragma unroll
            for (int c3 = 0; c3 < 8; c3++)
                qc += xb[c3] * Wq[(h * 8 + c) * 8 + c3];
            a += qc * Wk[c * 8 + c2];
        }
        sqk[qcol * 64 + h * 8 + c2] = a * (SCALE / 1024.0f);
    }
    __syncthreads();   // S3

    // ---- phase 2: exp logits cached in p (static idx) + denominator ----
    const float4* sqk4 = (const float4*)sqk;
    float p[R][8];
    {
        float e[8];
#pragma unroll
        for (int h = 0; h < 8; h++) {
            float4 q0 = sqk4[col * 16 + h * 2], q1 = sqk4[col * 16 + h * 2 + 1];
            float s = 0.f;
#pragma unroll
            for (int r = 0; r < R; r++) {
                p[r][h] = __expf(dot8p(x2[r], q0, q1));
                s += p[r][h];
            }
            e[h] = s;
        }
#pragma unroll
        for (int d = 2; d < 64; d <<= 1)
#pragma unroll
            for (int h = 0; h < 8; h++) e[h] += __shfl_xor(e[h], d, 64);
        if ((t & 63) < 2) {
#pragma unroll
            for (int h = 0; h < 8; h++) swred[w * 16 + col * 8 + h] = e[h];
        }
    }
    __syncthreads();   // S4
    if (t < 16) {
        float s = 0.f;
#pragma unroll
        for (int ww = 0; ww < 16; ww++) s += swred[ww * 16 + t];
        srden[t] = 1.0f / s;
    }
    __syncthreads();   // S5

    // ppair[h] = {p0h, p1h} * 1/den  (static idx, packed)
    f32x2 ppair[8];
#pragma unroll
    for (int h = 0; h < 8; h++) {
        float rd = srden[col * 8 + h];
        ppair[h].x = p[0][h] * rd;
        ppair[h].y = p[1][h] * rd;
    }

    // ---- phase 3: FULLY unrolled, r-paired packed output contraction.
    //      ALL weights via LDS ds_read_b128 (no in-loop s_loads). ----
    const float4* sWv4 = (const float4*)sWv;
    const float4* sWg4 = (const float4*)sWg;
    const float4* sWoT4 = (const float4*)sWoT;

    f32x2 oacc2[R][4];
#pragma unroll
    for (int r = 0; r < R; r++)
#pragma unroll
        for (int j = 0; j < 4; j++) {
            oacc2[r][j].x = bo[2 * j]; oacc2[r][j].y = bo[2 * j + 1];
        }

#pragma unroll
    for (int c = 0; c < 8; c++) {
        float4 wv0 = sWv4[c * 2], wv1 = sWv4[c * 2 + 1];
        f32x2 vpair;
        vpair.x = dot8p(x2[0], wv0, wv1);
        vpair.y = dot8p(x2[1], wv0, wv1);
#pragma unroll
        for (int h = 0; h < 8; h++) {
            int hc = h * 8 + c;
            float4 wg0 = sWg4[hc * 2], wg1 = sWg4[hc * 2 + 1];
            float4 woA = sWoT4[hc * 2];      // ds_read_b128
            float4 woB = sWoT4[hc * 2 + 1];
            f32x2 wo0; wo0.x = woA.x; wo0.y = woA.y;
            f32x2 wo1; wo1.x = woA.z; wo1.y = woA.w;
            f32x2 wo2; wo2.x = woB.x; wo2.y = woB.y;
            f32x2 wo3; wo3.x = woB.z; wo3.y = woB.w;
            float z0 = dot8p(x2[0], wg0, wg1);
            float z1 = dot8p(x2[1], wg0, wg1);
            f32x2 ez; ez.x = __expf(-z0); ez.y = __expf(-z1);
            f32x2 den = ez + 1.0f;                       // pk_add
            f32x2 g;
            g.x = __builtin_amdgcn_rcpf(den.x);
            g.y = __builtin_amdgcn_rcpf(den.y);
            f32x2 o = g * ppair[h] * vpair;              // 2 pk_mul
            f32x2 o0; o0.x = o.x; o0.y = o.x;            // op_sel splats
            f32x2 o1; o1.x = o.y; o1.y = o.y;
            oacc2[0][0] = o0 * wo0 + oacc2[0][0];
            oacc2[0][1] = o0 * wo1 + oacc2[0][1];
            oacc2[0][2] = o0 * wo2 + oacc2[0][2];
            oacc2[0][3] = o0 * wo3 + oacc2[0][3];
            oacc2[1][0] = o1 * wo0 + oacc2[1][0];
            oacc2[1][1] = o1 * wo1 + oacc2[1][1];
            oacc2[1][2] = o1 * wo2 + oacc2[1][2];
            oacc2[1][3] = o1 * wo3 + oacc2[1][3];
        }
    }
    float4* out4 = (float4*)out;
#pragma unroll
    for (int r = 0; r < R; r++) {
        int row = (si + 512 * r) * I + i;
        out4[row * 2] = make_float4(oacc2[r][0].x, oacc2[r][0].y,
                                    oacc2[r][1].x, oacc2[r][1].y);
        out4[row * 2 + 1] = make_float4(oacc2[r][2].x, oacc2[r][2].y,
                                        oacc2[r][3].x, oacc2[r][3].y);
    }
}

extern "C" void kernel_launch(void* const* d_in, const int* in_sizes, int n_in,
                              void* d_out, int out_size, void* d_ws, size_t ws_size,
                              hipStream_t stream) {
    const float* m     = (const float*)d_in[0];
    const float* gamma = (const float*)d_in[1];
    const float* beta  = (const float*)d_in[2];
    const float* Wq    = (const float*)d_in[3];
    const float* Wk    = (const float*)d_in[4];
    const float* Wv    = (const float*)d_in[5];
    const float* Wg    = (const float*)d_in[6];
    const float* Wo    = (const float*)d_in[7];
    const float* bo    = (const float*)d_in[8];
    float* out = (float*)d_out;

    fused<<<I / 2, 1024, 0, stream>>>(m, gamma, beta, Wq, Wk, Wv, Wg, Wo, bo, out);
}